// Round 5
// baseline (207.389 us; speedup 1.0000x reference)
//
#include <hip/hip_runtime.h>
#include <hip/hip_bf16.h>

// Problem constants
#define B_    4
#define T_    4096
#define C_    512
#define H_    8
#define D_    64
#define KS_   9
#define PAD_  4
#define MTOT  (B_ * T_)          // 16384
#define PLANE (MTOT * C_)        // elements per q/k/v plane
#define WU    (C_ * C_ / 8)      // weight units of 8 elements

typedef __bf16 bf16_t;
typedef __bf16 bf16x8 __attribute__((ext_vector_type(8)));
typedef float  f32x4  __attribute__((ext_vector_type(4)));

// ---------------------------------------------------------------------------
// fp32 -> bf16 for the 4 weight matrices AND x (GEMM A consumed via
// global_load_lds which cannot convert). 4*WU + PLANE/8 units, 8 elem each.
// ---------------------------------------------------------------------------
__global__ __launch_bounds__(256)
void conv_all(const float* __restrict__ Wq, const float* __restrict__ Wk,
              const float* __restrict__ Wv, const float* __restrict__ Wo,
              const float* __restrict__ x,
              bf16_t* __restrict__ Wb, bf16_t* __restrict__ xb) {
  int i = blockIdx.x * 256 + threadIdx.x;
  const float* src;
  bf16_t* dst;
  if (i < 4 * WU) {                        // WU = 1<<15
    int w = i >> 15;
    const float* W = (w == 0) ? Wq : (w == 1) ? Wk : (w == 2) ? Wv : Wo;
    src = W + (size_t)(i & (WU - 1)) * 8;
    dst = Wb + (size_t)i * 8;
  } else {
    size_t j = (size_t)(i - 4 * WU);
    src = x + j * 8;
    dst = xb + j * 8;
  }
  float4 f0 = ((const float4*)src)[0];
  float4 f1 = ((const float4*)src)[1];
  bf16x8 o;
  o[0] = (bf16_t)f0.x; o[1] = (bf16_t)f0.y; o[2] = (bf16_t)f0.z; o[3] = (bf16_t)f0.w;
  o[4] = (bf16_t)f1.x; o[5] = (bf16_t)f1.y; o[6] = (bf16_t)f1.z; o[7] = (bf16_t)f1.w;
  *(bf16x8*)dst = o;
}

// ---------------------------------------------------------------------------
// GEMM, round-5 structure: A via ring-3 LDS (gload_lds, XOR chunk swizzle,
// as verified r1-r4); B fragments loaded DIRECTLY to registers from global
// (weights are L2-resident; fragment = contiguous bf16x8), double-buffered
// one K-tile ahead. Rationale: r3~r4 flat across 2x barrier-count change ->
// main loop is LDS-pipe-bound (A 64KB + B 64KB reads + 48KB staging writes
// ~ 176KB/tile/CU vs 310cyc MFMA). B-direct cuts LDS traffic 45% and moves
// B onto the idle VMEM/L1 pipe.
//   C[m][n] = sum_k A[m][k] * Bw[n][k]   (+bias in epilogue)
// BM=256 x BN=128, BK=64, 8 waves as 4m x 2n -> per-wave 64x64 output.
// ONE barrier per K-tile (ring boundary). Correctness: per-wave vmcnt queue
// order [.. A(kt+1), B(kt), A(kt+2), B(kt+1)] means the compiler-inserted
// wait for B(kt) register operands also lands A(kt+1) gload_lds; boundary
// barrier then makes slot kt+1 globally visible. Explicit counted vmcnt at
// the boundary documents/backs this (never 0 mid-loop, T4).
// MODE 0: A = xb bf16 [MTOT][C], Bw = Wq|Wk|Wv packed, out -> qkv planes.
// MODE 1: A = y bf16 per-head planes (K-tile kt == head kt), out fp32.
// ---------------------------------------------------------------------------
#define BM   256
#define BN   128
#define BK   64
#define NKT  (C_ / BK)            // 8
#define ASL  (BM * BK)            // 16384 elems per A slot (32KB)

#define GLD(srcp, off) __builtin_amdgcn_global_load_lds(                     \
    (const __attribute__((address_space(1))) unsigned int*)(srcp),           \
    (__attribute__((address_space(3))) unsigned int*)(&sm[off]), 16, 0, 0)

template<int MODE>
__global__ __launch_bounds__(512, 2)
void gemm8p(const bf16_t* __restrict__ A, const bf16_t* __restrict__ Bw,
            const float* __restrict__ b0, const float* __restrict__ b1,
            const float* __restrict__ b2, void* __restrict__ Outp) {
  __shared__ __align__(16) bf16_t sm[3 * ASL];   // 96 KB

  constexpr int GX  = (MODE == 0) ? (3 * C_ / BN) : (C_ / BN);  // 12 / 4
  constexpr int NWG = GX * (MTOT / BM);                         // 768 / 256
  constexpr int CPX = NWG / 8;                                  // NWG%8==0

  // XCD swizzle (m157): consecutive logical n-blocks (sharing an A panel)
  // land on one XCD's L2.
  const int ord = blockIdx.y * GX + blockIdx.x;
  const int lg  = (ord & 7) * CPX + (ord >> 3);
  const int n0  = (lg % GX) * BN;
  const int m0  = (lg / GX) * BM;

  const int tid  = threadIdx.x;
  const int lane = tid & 63;
  const int wave = tid >> 6;
  const int wm   = wave >> 1;          // 0..3  (64-row slice)
  const int wn   = wave & 1;           // 0..1  (64-col slice)
  const int lr   = lane & 15;          // fragment row
  const int lq   = lane >> 4;          // k-group

  // A staging sources (inverse-swizzled global addresses), 4 units/thread.
  const bf16_t* aSrc[4];
#pragma unroll
  for (int s = 0; s < 4; ++s) {
    int u = s * 512 + tid, r = u >> 3, ch = u & 7;
    int cs = (ch ^ (r & 7)) << 3;
    if constexpr (MODE == 0) {
      aSrc[s] = A + (size_t)(m0 + r) * C_ + cs;
    } else {
      int bb = m0 >> 12, t0 = m0 & (T_ - 1);
      aSrc[s] = A + ((size_t)bb * H_ * T_ + t0 + r) * D_ + cs;  // head 0 base
    }
  }
  constexpr size_t ASTEP = (MODE == 0) ? (size_t)BK : (size_t)T_ * D_;

  // B fragment base addresses (4/thread): frag(kt,j,kk) is the contiguous
  // bf16x8 at bBase[j] + kt*64 + kk*32 (byte offsets <=960 -> immediates).
  const bf16_t* bBase[4];
#pragma unroll
  for (int j = 0; j < 4; ++j)
    bBase[j] = Bw + (size_t)(n0 + wn * 64 + j * 16 + lr) * C_ + lq * 8;

  // Prologue: A(0)->slot0, A(1)->slot1 (in flight), B(0)->regs.
#pragma unroll
  for (int s = 0; s < 4; ++s) GLD(aSrc[s], (s * 512 + tid) * 8);
#pragma unroll
  for (int s = 0; s < 4; ++s) GLD(aSrc[s] + ASTEP, ASL + (s * 512 + tid) * 8);
  bf16x8 bfr[2][4][2];                 // [tile parity][n-frag][kk]
#pragma unroll
  for (int j = 0; j < 4; ++j) {
    bfr[0][j][0] = *(const bf16x8*)(bBase[j]);
    bfr[0][j][1] = *(const bf16x8*)(bBase[j] + 32);
  }
  // outstanding: A0(4, oldest) A1(4) B0(8) -> land A0 only
  asm volatile("s_waitcnt vmcnt(12)" ::: "memory");
  __builtin_amdgcn_s_barrier();

  f32x4 acc[4][4] = {};
  const int co0 = ((0 + lq) ^ (lane & 7)) << 3;    // swizzled chunk, kk=0
  const int co1 = ((4 + lq) ^ (lane & 7)) << 3;    // kk=1

#pragma unroll
  for (int kt = 0; kt < NKT; ++kt) {
    const int rsl = kt % 3;
    const int wof = ((kt + 2) % 3) * ASL;
    const bf16_t* arow = &sm[rsl * ASL + (wm * 64 + lr) * 64];

    // ds_read A fragments (8 x b128) -- slot rsl is full (prev boundary).
    bf16x8 af[4][2];
#pragma unroll
    for (int i = 0; i < 4; ++i) {
      af[i][0] = *(const bf16x8*)(arow + i * 1024 + co0);
      af[i][1] = *(const bf16x8*)(arow + i * 1024 + co1);
    }
    // Stage A(kt+2) -> slot (kt+2)%3 (its readers finished before the
    // kt-1 boundary barrier).
    if (kt + 2 < NKT) {
#pragma unroll
      for (int s = 0; s < 4; ++s)
        GLD(aSrc[s] + (size_t)(kt + 2) * ASTEP, wof + (s * 512 + tid) * 8);
    }
    // Prefetch B(kt+1) -> other register buffer (plain global loads).
    if (kt + 1 < NKT) {
#pragma unroll
      for (int j = 0; j < 4; ++j) {
        bfr[(kt + 1) & 1][j][0] =
            *(const bf16x8*)(bBase[j] + (kt + 1) * 64);
        bfr[(kt + 1) & 1][j][1] =
            *(const bf16x8*)(bBase[j] + (kt + 1) * 64 + 32);
      }
    }
    __builtin_amdgcn_sched_barrier(0);
    asm volatile("s_waitcnt lgkmcnt(0)" ::: "memory");   // af landed
    __builtin_amdgcn_sched_barrier(0);
    __builtin_amdgcn_s_setprio(1);
#pragma unroll
    for (int i = 0; i < 4; ++i)
#pragma unroll
      for (int j = 0; j < 4; ++j)
#pragma unroll
        for (int kk = 0; kk < 2; ++kk)
          acc[i][j] = __builtin_amdgcn_mfma_f32_16x16x32_bf16(
              af[i][kk], bfr[kt & 1][j][kk], acc[i][j], 0, 0, 0);
    __builtin_amdgcn_s_setprio(0);
    __builtin_amdgcn_sched_barrier(0);
    // Boundary: counted vmcnt (A(kt+1) already landed via the B(kt)
    // register waits -- same per-wave queue, older entries). Never 0.
    if (kt + 2 < NKT)      asm volatile("s_waitcnt vmcnt(12)" ::: "memory");
    else if (kt + 2 == NKT) asm volatile("s_waitcnt vmcnt(8)" ::: "memory");
    if (kt + 1 < NKT) __builtin_amdgcn_s_barrier();
  }

  // Epilogue. C/D layout: col = lane&15, row = (lane>>4)*4 + reg  [m89]
  const int cn = lane & 15;
  const int rq = (lane >> 4) << 2;
  if constexpr (MODE == 0) {
    const int z  = n0 >> 9;                        // BN=128 | 512 -> z uniform
    const float* bias = (z == 0) ? b0 : (z == 1) ? b1 : b2;
    const int bb = m0 >> 12;
    const int t0 = m0 & (T_ - 1);
    bf16_t* plane = (bf16_t*)Outp + (size_t)z * PLANE;
#pragma unroll
    for (int j = 0; j < 4; ++j) {
      const int cc  = (n0 & (C_ - 1)) + wn * 64 + j * 16 + cn;
      const int hh  = cc >> 6, dd = cc & 63;
      const float bvv = bias[cc];
      bf16_t* hb = plane + ((size_t)(bb * H_ + hh) * T_) * D_ + dd;
#pragma unroll
      for (int i = 0; i < 4; ++i)
#pragma unroll
        for (int r = 0; r < 4; ++r) {
          const int t = t0 + wm * 64 + i * 16 + rq + r;
          hb[(size_t)t * D_] = (bf16_t)(acc[i][j][r] + bvv);
        }
    }
  } else {
    float* outp = (float*)Outp;
#pragma unroll
    for (int j = 0; j < 4; ++j) {
      const int n = n0 + wn * 64 + j * 16 + cn;
      const float bvv = b0[n];
#pragma unroll
      for (int i = 0; i < 4; ++i)
#pragma unroll
        for (int r = 0; r < 4; ++r) {
          const int m = m0 + wm * 64 + i * 16 + rq + r;
          outp[(size_t)m * C_ + n] = acc[i][j][r] + bvv;
        }
    }
  }
}

// ---------------------------------------------------------------------------
// Neighborhood attention: 8 threads per (b,h,t), d-octet each; width-8
// shfl_xor score reduce; per-head plane I/O (fully coalesced). Unchanged.
// ---------------------------------------------------------------------------
__global__ __launch_bounds__(256)
void attn_kernel(const bf16_t* __restrict__ qkv, bf16_t* __restrict__ y) {
  const int tid  = threadIdx.x;
  const int sub  = tid & 7;
  const int tl   = tid >> 3;
  const int t    = blockIdx.x * 32 + tl;
  const int h    = blockIdx.y;
  const int b    = blockIdx.z;

  const size_t pl = (size_t)(b * H_ + h) * T_ * D_;
  const bf16_t* q = qkv + pl;
  const bf16_t* k = qkv + (size_t)PLANE + pl;
  const bf16_t* v = qkv + (size_t)2 * PLANE + pl;
  const int c = sub * 8;

  int tj[KS_];
#pragma unroll
  for (int j = 0; j < KS_; ++j) {
    int tt = t - PAD_ + j;
    tj[j] = tt < 0 ? 0 : (tt >= T_ ? T_ - 1 : tt);
  }

  bf16x8 q8 = *(const bf16x8*)(q + (size_t)t * D_ + c);
  float qf[8];
#pragma unroll
  for (int e = 0; e < 8; ++e) qf[e] = (float)q8[e];

  float s[KS_];
#pragma unroll
  for (int j = 0; j < KS_; ++j) {
    bf16x8 k8 = *(const bf16x8*)(k + (size_t)tj[j] * D_ + c);
    float d0 = 0.f;
#pragma unroll
    for (int e = 0; e < 8; ++e) d0 += qf[e] * (float)k8[e];
    s[j] = d0;
  }

#pragma unroll
  for (int m = 1; m < 8; m <<= 1)
#pragma unroll
    for (int j = 0; j < KS_; ++j) s[j] += __shfl_xor(s[j], m, 8);

  float mx = s[0];
#pragma unroll
  for (int j = 1; j < KS_; ++j) mx = fmaxf(mx, s[j]);
  float w[KS_], sum = 0.f;
#pragma unroll
  for (int j = 0; j < KS_; ++j) {
    w[j] = __expf((s[j] - mx) * 0.125f);   // scale = 1/sqrt(64)
    sum += w[j];
  }
  const float inv = 1.f / sum;
#pragma unroll
  for (int j = 0; j < KS_; ++j) w[j] *= inv;

  float o[8] = {0.f, 0.f, 0.f, 0.f, 0.f, 0.f, 0.f, 0.f};
#pragma unroll
  for (int j = 0; j < KS_; ++j) {
    bf16x8 v8 = *(const bf16x8*)(v + (size_t)tj[j] * D_ + c);
#pragma unroll
    for (int e = 0; e < 8; ++e) o[e] += w[j] * (float)v8[e];
  }
  bf16x8 o8;
#pragma unroll
  for (int e = 0; e < 8; ++e) o8[e] = (bf16_t)o[e];
  *(bf16x8*)(y + pl + (size_t)t * D_ + c) = o8;
}

// ---------------------------------------------------------------------------
extern "C" void kernel_launch(void* const* d_in, const int* in_sizes, int n_in,
                              void* d_out, int out_size, void* d_ws, size_t ws_size,
                              hipStream_t stream) {
  const float* x  = (const float*)d_in[0];
  const float* Wq = (const float*)d_in[1];
  const float* bq = (const float*)d_in[2];
  const float* Wk = (const float*)d_in[3];
  const float* bk = (const float*)d_in[4];
  const float* Wv = (const float*)d_in[5];
  const float* bv = (const float*)d_in[6];
  const float* Wo = (const float*)d_in[7];
  const float* bo = (const float*)d_in[8];
  float* out = (float*)d_out;

  // Workspace: Wb 2MB | xb 16.8MB | qkv 50.3MB  (y aliases xb: xb is dead
  // once gemm8p<0> completes; attn writes y, gemm8p<1> reads it). ~69MB.
  bf16_t* Wb  = (bf16_t*)d_ws;
  bf16_t* xb  = Wb + (size_t)4 * C_ * C_;
  bf16_t* qkv = xb + (size_t)PLANE;
  bf16_t* y   = xb;

  conv_all<<<(4 * WU + PLANE / 8) / 256, 256, 0, stream>>>(Wq, Wk, Wv, Wo, x, Wb, xb);
  gemm8p<0><<<dim3(3 * C_ / BN, MTOT / BM), 512, 0, stream>>>(
      xb, Wb, bq, bk, bv, qkv);
  attn_kernel<<<dim3(T_ / 32, H_, B_), 256, 0, stream>>>(qkv, y);
  gemm8p<1><<<dim3(C_ / BN, MTOT / BM), 512, 0, stream>>>(
      y, Wb + (size_t)3 * C_ * C_, bo, nullptr, nullptr, out);
}

// Round 6
// 167.316 us; speedup vs baseline: 1.2395x; 1.2395x over previous
//
#include <hip/hip_runtime.h>
#include <hip/hip_bf16.h>

// Problem constants
#define B_    4
#define T_    4096
#define C_    512
#define H_    8
#define D_    64
#define KS_   9
#define PAD_  4
#define MTOT  (B_ * T_)          // 16384
#define PLANE (MTOT * C_)        // elements per q/k/v plane
#define WU    (C_ * C_ / 8)      // weight units of 8 elements

typedef __bf16 bf16_t;
typedef __bf16 bf16x8 __attribute__((ext_vector_type(8)));
typedef float  f32x4  __attribute__((ext_vector_type(4)));

// ---------------------------------------------------------------------------
// fp32 -> bf16 for the 4 weight matrices AND x (GEMM A consumed via
// global_load_lds which cannot convert). 4*WU + PLANE/8 units, 8 elem each.
// ---------------------------------------------------------------------------
__global__ __launch_bounds__(256)
void conv_all(const float* __restrict__ Wq, const float* __restrict__ Wk,
              const float* __restrict__ Wv, const float* __restrict__ Wo,
              const float* __restrict__ x,
              bf16_t* __restrict__ Wb, bf16_t* __restrict__ xb) {
  int i = blockIdx.x * 256 + threadIdx.x;
  const float* src;
  bf16_t* dst;
  if (i < 4 * WU) {                        // WU = 1<<15
    int w = i >> 15;
    const float* W = (w == 0) ? Wq : (w == 1) ? Wk : (w == 2) ? Wv : Wo;
    src = W + (size_t)(i & (WU - 1)) * 8;
    dst = Wb + (size_t)i * 8;
  } else {
    size_t j = (size_t)(i - 4 * WU);
    src = x + j * 8;
    dst = xb + j * 8;
  }
  float4 f0 = ((const float4*)src)[0];
  float4 f1 = ((const float4*)src)[1];
  bf16x8 o;
  o[0] = (bf16_t)f0.x; o[1] = (bf16_t)f0.y; o[2] = (bf16_t)f0.z; o[3] = (bf16_t)f0.w;
  o[4] = (bf16_t)f1.x; o[5] = (bf16_t)f1.y; o[6] = (bf16_t)f1.z; o[7] = (bf16_t)f1.w;
  *(bf16x8*)dst = o;
}

// ---------------------------------------------------------------------------
// GEMM round 6: OCCUPANCY-FIRST. r1-r4 ran 144KB LDS -> 1 block/CU (the
// counters said so all along: LDS_Block_Size 147456, Occupancy ~18%), so
// every barrier/drain stalled the whole CU; r5's B-direct regressed on
// VMEM line-request serialization. This round: BM=128 x BN=128, BK=32,
// ring-3 of 16KB slots = 48KB LDS -> 3 blocks/CU (12 waves), 256 thr /
// 4 waves (2m x 2n, 64x64 per wave). Per-CU floor: MFMA ~10.8us > LDS
// ~7.5us -> MFMA-limited at last. Pipeline retained from r1-r4 (verified):
// ring-3 staging 2 tiles ahead via global_load_lds, counted vmcnt(4) at
// the boundary (kt+2's 4 loads stay in flight; 0 only at the last staged
// boundary), setprio around the 16-MFMA cluster, ONE barrier per K-tile.
//   Slot-disjointness: during kt, GLDs write slot (kt+2)%3, ds_reads hit
//   slot kt%3; readers of slot s finish (lgkm-drained) before the kt
//   boundary barrier, and its next writer issues only after that barrier.
// XOR chunk swizzle (r0-verified, BK=32: 4 chunks of 16B per 64B row):
//   LDS slot sl of row r holds global chunk sl^((r>>1)&3); ds_read with
//   co = (lq^((lr>>1)&3))*8 -> 2-way bank aliasing = free (m136).
// MODE 0: A = xb bf16 [MTOT][C], Bw = Wq|Wk|Wv packed, out -> qkv planes.
// MODE 1: A = y bf16 per-head planes (K-tile kt -> head kt>>1), out fp32.
// ---------------------------------------------------------------------------
#define BM   128
#define BN   128
#define BK   32
#define NKT  (C_ / BK)            // 16
#define ASL  (BM * BK)            // 4096 elems per A slot (8KB)
#define SLOT (2 * ASL)            // A + B = 8192 elems (16KB)

#define GLD(srcp, off) __builtin_amdgcn_global_load_lds(                     \
    (const __attribute__((address_space(1))) unsigned int*)(srcp),           \
    (__attribute__((address_space(3))) unsigned int*)(&sm[off]), 16, 0, 0)

template<int MODE>
__global__ __launch_bounds__(256, 3)
void gemm8p(const bf16_t* __restrict__ A, const bf16_t* __restrict__ Bw,
            const float* __restrict__ b0, const float* __restrict__ b1,
            const float* __restrict__ b2, void* __restrict__ Outp) {
  __shared__ __align__(16) bf16_t sm[3 * SLOT];   // 48 KB

  constexpr int GX  = (MODE == 0) ? (3 * C_ / BN) : (C_ / BN);  // 12 / 4
  constexpr int NWG = GX * (MTOT / BM);                         // 1536 / 512
  constexpr int CPX = NWG / 8;                                  // NWG%8==0

  // XCD swizzle (m157): consecutive logical n-blocks (sharing an A panel)
  // land on one XCD's L2.
  const int ord = blockIdx.y * GX + blockIdx.x;
  const int lg  = (ord & 7) * CPX + (ord >> 3);
  const int n0  = (lg % GX) * BN;
  const int m0  = (lg / GX) * BM;

  const int tid  = threadIdx.x;
  const int lane = tid & 63;
  const int wave = tid >> 6;
  const int wm   = wave >> 1;          // 0..1  (64-row slice)
  const int wn   = wave & 1;           // 0..1  (64-col slice)
  const int lr   = lane & 15;          // fragment row
  const int lq   = lane >> 4;          // k-chunk of the fragment

  // Staging sources (inverse-swizzled global addresses).
  // A: 512 16B units (2/thread); B: 512 units (2/thread).
  const bf16_t* aSrc[2];
  const bf16_t* bSrc[2];
#pragma unroll
  for (int s = 0; s < 2; ++s) {
    int u = s * 256 + tid, r = u >> 2, sl = u & 3;
    int cs = (sl ^ ((r >> 1) & 3)) << 3;
    if constexpr (MODE == 0) {
      aSrc[s] = A + (size_t)(m0 + r) * C_ + cs;
    } else {
      int bb = m0 >> 12, t0 = m0 & (T_ - 1);
      aSrc[s] = A + ((size_t)bb * H_ * T_ + t0 + r) * D_ + cs;  // head 0 base
    }
    bSrc[s] = Bw + (size_t)(n0 + r) * C_ + cs;
  }
  // K-tile element offset within the A source. MODE 1: head kt>>1, half kt&1.
  auto ofsA = [](int kt) -> size_t {
    if constexpr (MODE == 0) return (size_t)kt * BK;
    else return (size_t)(kt >> 1) * ((size_t)T_ * D_) + (size_t)(kt & 1) * 32;
  };

  // Prologue: kt0 -> slot0, kt1 -> slot1; wait kt0 only (kt1's 4 in flight).
#pragma unroll
  for (int s = 0; s < 2; ++s) GLD(aSrc[s] + ofsA(0), (s * 256 + tid) * 8);
#pragma unroll
  for (int s = 0; s < 2; ++s) GLD(bSrc[s], ASL + (s * 256 + tid) * 8);
#pragma unroll
  for (int s = 0; s < 2; ++s) GLD(aSrc[s] + ofsA(1), SLOT + (s * 256 + tid) * 8);
#pragma unroll
  for (int s = 0; s < 2; ++s) GLD(bSrc[s] + BK, SLOT + ASL + (s * 256 + tid) * 8);
  asm volatile("s_waitcnt vmcnt(4)" ::: "memory");
  __builtin_amdgcn_s_barrier();

  f32x4 acc[4][4] = {};
  const int co = ((lq ^ ((lr >> 1) & 3)) << 3);   // swizzled chunk offset

#pragma unroll
  for (int kt = 0; kt < NKT; ++kt) {
    const int rsl = kt % 3;
    const int wof = ((kt + 2) % 3) * SLOT;
    const bf16_t* abase = &sm[rsl * SLOT + (wm * 64 + lr) * BK + co];
    const bf16_t* bbase = &sm[rsl * SLOT + ASL + (wn * 64 + lr) * BK + co];

    // ds_read the 8 fragments (b128 each); slot rsl full since boundary kt-1.
    bf16x8 af[4], bfr[4];
#pragma unroll
    for (int i = 0; i < 4; ++i) {
      af[i]  = *(const bf16x8*)(abase + i * (16 * BK));
      bfr[i] = *(const bf16x8*)(bbase + i * (16 * BK));
    }
    // Stage kt+2 -> slot (kt+2)%3 (readers finished before boundary kt-1).
    if (kt + 2 < NKT) {
#pragma unroll
      for (int s = 0; s < 2; ++s)
        GLD(aSrc[s] + ofsA(kt + 2), wof + (s * 256 + tid) * 8);
#pragma unroll
      for (int s = 0; s < 2; ++s)
        GLD(bSrc[s] + (size_t)(kt + 2) * BK, wof + ASL + (s * 256 + tid) * 8);
    }
    __builtin_amdgcn_sched_barrier(0);
    asm volatile("s_waitcnt lgkmcnt(0)" ::: "memory");   // fragments landed
    __builtin_amdgcn_sched_barrier(0);
    __builtin_amdgcn_s_setprio(1);
#pragma unroll
    for (int i = 0; i < 4; ++i)
#pragma unroll
      for (int j = 0; j < 4; ++j)
        acc[i][j] = __builtin_amdgcn_mfma_f32_16x16x32_bf16(
            af[i], bfr[j], acc[i][j], 0, 0, 0);
    __builtin_amdgcn_s_setprio(0);
    __builtin_amdgcn_sched_barrier(0);
    // Boundary: counted vmcnt (T4) -- kt+1's 4 loads landed, kt+2's 4 stay
    // in flight. vmcnt(0) only at the last staged boundary.
    if (kt + 2 < NKT)       asm volatile("s_waitcnt vmcnt(4)" ::: "memory");
    else if (kt + 2 == NKT) asm volatile("s_waitcnt vmcnt(0)" ::: "memory");
    if (kt + 1 < NKT) __builtin_amdgcn_s_barrier();
  }

  // Epilogue. C/D layout: col = lane&15, row = (lane>>4)*4 + reg  [m89]
  const int cn = lane & 15;
  const int rq = (lane >> 4) << 2;
  if constexpr (MODE == 0) {
    const int z  = n0 >> 9;                        // BN=128 | 512 -> z uniform
    const float* bias = (z == 0) ? b0 : (z == 1) ? b1 : b2;
    const int bb = m0 >> 12;
    const int t0 = m0 & (T_ - 1);
    bf16_t* plane = (bf16_t*)Outp + (size_t)z * PLANE;
#pragma unroll
    for (int j = 0; j < 4; ++j) {
      const int cc  = (n0 & (C_ - 1)) + wn * 64 + j * 16 + cn;
      const int hh  = cc >> 6, dd = cc & 63;
      const float bvv = bias[cc];
      bf16_t* hb = plane + ((size_t)(bb * H_ + hh) * T_) * D_ + dd;
#pragma unroll
      for (int i = 0; i < 4; ++i)
#pragma unroll
        for (int r = 0; r < 4; ++r) {
          const int t = t0 + wm * 64 + i * 16 + rq + r;
          hb[(size_t)t * D_] = (bf16_t)(acc[i][j][r] + bvv);
        }
    }
  } else {
    float* outp = (float*)Outp;
#pragma unroll
    for (int j = 0; j < 4; ++j) {
      const int n = n0 + wn * 64 + j * 16 + cn;
      const float bvv = b0[n];
#pragma unroll
      for (int i = 0; i < 4; ++i)
#pragma unroll
        for (int r = 0; r < 4; ++r) {
          const int m = m0 + wm * 64 + i * 16 + rq + r;
          outp[(size_t)m * C_ + n] = acc[i][j][r] + bvv;
        }
    }
  }
}

// ---------------------------------------------------------------------------
// Neighborhood attention: 8 threads per (b,h,t), d-octet each; width-8
// shfl_xor score reduce; per-head plane I/O (fully coalesced). Unchanged.
// ---------------------------------------------------------------------------
__global__ __launch_bounds__(256)
void attn_kernel(const bf16_t* __restrict__ qkv, bf16_t* __restrict__ y) {
  const int tid  = threadIdx.x;
  const int sub  = tid & 7;
  const int tl   = tid >> 3;
  const int t    = blockIdx.x * 32 + tl;
  const int h    = blockIdx.y;
  const int b    = blockIdx.z;

  const size_t pl = (size_t)(b * H_ + h) * T_ * D_;
  const bf16_t* q = qkv + pl;
  const bf16_t* k = qkv + (size_t)PLANE + pl;
  const bf16_t* v = qkv + (size_t)2 * PLANE + pl;
  const int c = sub * 8;

  int tj[KS_];
#pragma unroll
  for (int j = 0; j < KS_; ++j) {
    int tt = t - PAD_ + j;
    tj[j] = tt < 0 ? 0 : (tt >= T_ ? T_ - 1 : tt);
  }

  bf16x8 q8 = *(const bf16x8*)(q + (size_t)t * D_ + c);
  float qf[8];
#pragma unroll
  for (int e = 0; e < 8; ++e) qf[e] = (float)q8[e];

  float s[KS_];
#pragma unroll
  for (int j = 0; j < KS_; ++j) {
    bf16x8 k8 = *(const bf16x8*)(k + (size_t)tj[j] * D_ + c);
    float d0 = 0.f;
#pragma unroll
    for (int e = 0; e < 8; ++e) d0 += qf[e] * (float)k8[e];
    s[j] = d0;
  }

#pragma unroll
  for (int m = 1; m < 8; m <<= 1)
#pragma unroll
    for (int j = 0; j < KS_; ++j) s[j] += __shfl_xor(s[j], m, 8);

  float mx = s[0];
#pragma unroll
  for (int j = 1; j < KS_; ++j) mx = fmaxf(mx, s[j]);
  float w[KS_], sum = 0.f;
#pragma unroll
  for (int j = 0; j < KS_; ++j) {
    w[j] = __expf((s[j] - mx) * 0.125f);   // scale = 1/sqrt(64)
    sum += w[j];
  }
  const float inv = 1.f / sum;
#pragma unroll
  for (int j = 0; j < KS_; ++j) w[j] *= inv;

  float o[8] = {0.f, 0.f, 0.f, 0.f, 0.f, 0.f, 0.f, 0.f};
#pragma unroll
  for (int j = 0; j < KS_; ++j) {
    bf16x8 v8 = *(const bf16x8*)(v + (size_t)tj[j] * D_ + c);
#pragma unroll
    for (int e = 0; e < 8; ++e) o[e] += w[j] * (float)v8[e];
  }
  bf16x8 o8;
#pragma unroll
  for (int e = 0; e < 8; ++e) o8[e] = (bf16_t)o[e];
  *(bf16x8*)(y + pl + (size_t)t * D_ + c) = o8;
}

// ---------------------------------------------------------------------------
extern "C" void kernel_launch(void* const* d_in, const int* in_sizes, int n_in,
                              void* d_out, int out_size, void* d_ws, size_t ws_size,
                              hipStream_t stream) {
  const float* x  = (const float*)d_in[0];
  const float* Wq = (const float*)d_in[1];
  const float* bq = (const float*)d_in[2];
  const float* Wk = (const float*)d_in[3];
  const float* bk = (const float*)d_in[4];
  const float* Wv = (const float*)d_in[5];
  const float* bv = (const float*)d_in[6];
  const float* Wo = (const float*)d_in[7];
  const float* bo = (const float*)d_in[8];
  float* out = (float*)d_out;

  // Workspace: Wb 2MB | xb 16.8MB | qkv 50.3MB  (y aliases xb: xb is dead
  // once gemm8p<0> completes; attn writes y, gemm8p<1> reads it). ~69MB.
  bf16_t* Wb  = (bf16_t*)d_ws;
  bf16_t* xb  = Wb + (size_t)4 * C_ * C_;
  bf16_t* qkv = xb + (size_t)PLANE;
  bf16_t* y   = xb;

  conv_all<<<(4 * WU + PLANE / 8) / 256, 256, 0, stream>>>(Wq, Wk, Wv, Wo, x, Wb, xb);
  gemm8p<0><<<dim3(3 * C_ / BN, MTOT / BM), 256, 0, stream>>>(
      xb, Wb, bq, bk, bv, qkv);
  attn_kernel<<<dim3(T_ / 32, H_, B_), 256, 0, stream>>>(qkv, y);
  gemm8p<1><<<dim3(C_ / BN, MTOT / BM), 256, 0, stream>>>(
      y, Wb + (size_t)3 * C_ * C_, bo, nullptr, nullptr, out);
}

// Round 7
// 166.070 us; speedup vs baseline: 1.2488x; 1.0075x over previous
//
#include <hip/hip_runtime.h>
#include <hip/hip_bf16.h>

// Problem constants
#define B_    4
#define T_    4096
#define C_    512
#define H_    8
#define D_    64
#define KS_   9
#define PAD_  4
#define MTOT  (B_ * T_)          // 16384
#define PLANE (MTOT * C_)        // elements per q/k/v plane
#define WU    (C_ * C_ / 8)      // weight units of 8 elements

typedef __bf16 bf16_t;
typedef __bf16 bf16x8 __attribute__((ext_vector_type(8)));
typedef float  f32x4  __attribute__((ext_vector_type(4)));

// ---------------------------------------------------------------------------
// fp32 -> bf16 for the 4 weight matrices AND x (GEMM A consumed via
// global_load_lds which cannot convert). 4*WU + PLANE/8 units, 8 elem each.
// ---------------------------------------------------------------------------
__global__ __launch_bounds__(256)
void conv_all(const float* __restrict__ Wq, const float* __restrict__ Wk,
              const float* __restrict__ Wv, const float* __restrict__ Wo,
              const float* __restrict__ x,
              bf16_t* __restrict__ Wb, bf16_t* __restrict__ xb) {
  int i = blockIdx.x * 256 + threadIdx.x;
  const float* src;
  bf16_t* dst;
  if (i < 4 * WU) {                        // WU = 1<<15
    int w = i >> 15;
    const float* W = (w == 0) ? Wq : (w == 1) ? Wk : (w == 2) ? Wv : Wo;
    src = W + (size_t)(i & (WU - 1)) * 8;
    dst = Wb + (size_t)i * 8;
  } else {
    size_t j = (size_t)(i - 4 * WU);
    src = x + j * 8;
    dst = xb + j * 8;
  }
  float4 f0 = ((const float4*)src)[0];
  float4 f1 = ((const float4*)src)[1];
  bf16x8 o;
  o[0] = (bf16_t)f0.x; o[1] = (bf16_t)f0.y; o[2] = (bf16_t)f0.z; o[3] = (bf16_t)f0.w;
  o[4] = (bf16_t)f1.x; o[5] = (bf16_t)f1.y; o[6] = (bf16_t)f1.z; o[7] = (bf16_t)f1.w;
  *(bf16x8*)dst = o;
}

// ---------------------------------------------------------------------------
// GEMM round 7: r6 skeleton (BM=128 BN=128 BK=32, ring-3 of 16KB slots =
// 48KB LDS -> 3 blocks/CU, 4 waves 2mx2n, XOR chunk swizzle, counted
// vmcnt(4) boundary, ONE barrier/tile, setprio) MINUS the hand pins.
// r1-r6 falsified: barrier count (r3~r4), tile shape (r3), LDS traffic
// (r5 regressed), occupancy (r6 flat). The untested difference vs m97's
// 874TF loop: my sched_barrier(0)+lgkmcnt(0) pins force each wave to
// drain ALL 8 ds_reads (~120+cyc) before MFMA #1, every tile (m141's
// order-pinning landed at 510TF -- where we are). This round: let the
// compiler emit progressive lgkmcnt(4/3/1/0) and interleave reads/GLDs/
// MFMAs (m97 behavior, near-optimal per guide), while KEEPING counted
// vmcnt across the barrier (which m97 lacked: its barrier drained
// vmcnt(0); ours doesn't because in-flight GLDs target a disjoint slot).
//   Slot-disjointness/race-freedom (as r6, verified): during kt, GLDs
//   write slot (kt+2)%3, ds_reads hit kt%3; every wave executes vmcnt(4)
//   (its own kt+1 loads landed) before the boundary barrier; ds_reads
//   cannot hoist across s_barrier (LDS fence). No inline-asm ds_reads,
//   so compiler dependency tracking is sound (rule #18 n/a).
// XOR chunk swizzle (r0-verified, BK=32): LDS slot sl of row r holds
// global chunk sl^((r>>1)&3); read with co=(lq^((lr>>1)&3))*8 -> 2-way
// bank aliasing = free (m136).
// MODE 0: A = xb bf16 [MTOT][C], Bw = Wq|Wk|Wv packed, out -> qkv planes.
// MODE 1: A = y bf16 per-head planes (K-tile kt -> head kt>>1), out fp32.
// ---------------------------------------------------------------------------
#define BM   128
#define BN   128
#define BK   32
#define NKT  (C_ / BK)            // 16
#define ASL  (BM * BK)            // 4096 elems per A slot (8KB)
#define SLOT (2 * ASL)            // A + B = 8192 elems (16KB)

#define GLD(srcp, off) __builtin_amdgcn_global_load_lds(                     \
    (const __attribute__((address_space(1))) unsigned int*)(srcp),           \
    (__attribute__((address_space(3))) unsigned int*)(&sm[off]), 16, 0, 0)

template<int MODE>
__global__ __launch_bounds__(256, 3)
void gemm8p(const bf16_t* __restrict__ A, const bf16_t* __restrict__ Bw,
            const float* __restrict__ b0, const float* __restrict__ b1,
            const float* __restrict__ b2, void* __restrict__ Outp) {
  __shared__ __align__(16) bf16_t sm[3 * SLOT];   // 48 KB

  constexpr int GX  = (MODE == 0) ? (3 * C_ / BN) : (C_ / BN);  // 12 / 4
  constexpr int NWG = GX * (MTOT / BM);                         // 1536 / 512
  constexpr int CPX = NWG / 8;                                  // NWG%8==0

  // XCD swizzle (m157): each XCD owns contiguous logical tiles (complete
  // m-panels), so an A panel's 12 (or 4) n-tiles share one L2.
  const int ord = blockIdx.y * GX + blockIdx.x;
  const int lg  = (ord & 7) * CPX + (ord >> 3);
  const int n0  = (lg % GX) * BN;
  const int m0  = (lg / GX) * BM;

  const int tid  = threadIdx.x;
  const int lane = tid & 63;
  const int wave = tid >> 6;
  const int wm   = wave >> 1;          // 0..1  (64-row slice)
  const int wn   = wave & 1;           // 0..1  (64-col slice)
  const int lr   = lane & 15;          // fragment row
  const int lq   = lane >> 4;          // k-chunk of the fragment

  // Staging sources (inverse-swizzled global addresses).
  // A: 512 16B units (2/thread); B: 512 units (2/thread).
  const bf16_t* aSrc[2];
  const bf16_t* bSrc[2];
#pragma unroll
  for (int s = 0; s < 2; ++s) {
    int u = s * 256 + tid, r = u >> 2, sl = u & 3;
    int cs = (sl ^ ((r >> 1) & 3)) << 3;
    if constexpr (MODE == 0) {
      aSrc[s] = A + (size_t)(m0 + r) * C_ + cs;
    } else {
      int bb = m0 >> 12, t0 = m0 & (T_ - 1);
      aSrc[s] = A + ((size_t)bb * H_ * T_ + t0 + r) * D_ + cs;  // head 0 base
    }
    bSrc[s] = Bw + (size_t)(n0 + r) * C_ + cs;
  }
  // K-tile element offset within the A source. MODE 1: head kt>>1, half kt&1.
  auto ofsA = [](int kt) -> size_t {
    if constexpr (MODE == 0) return (size_t)kt * BK;
    else return (size_t)(kt >> 1) * ((size_t)T_ * D_) + (size_t)(kt & 1) * 32;
  };

  // Prologue: kt0 -> slot0, kt1 -> slot1; wait kt0 only (kt1's 4 in flight).
#pragma unroll
  for (int s = 0; s < 2; ++s) GLD(aSrc[s] + ofsA(0), (s * 256 + tid) * 8);
#pragma unroll
  for (int s = 0; s < 2; ++s) GLD(bSrc[s], ASL + (s * 256 + tid) * 8);
#pragma unroll
  for (int s = 0; s < 2; ++s) GLD(aSrc[s] + ofsA(1), SLOT + (s * 256 + tid) * 8);
#pragma unroll
  for (int s = 0; s < 2; ++s) GLD(bSrc[s] + BK, SLOT + ASL + (s * 256 + tid) * 8);
  asm volatile("s_waitcnt vmcnt(4)" ::: "memory");
  __builtin_amdgcn_s_barrier();

  f32x4 acc[4][4] = {};
  const int co = ((lq ^ ((lr >> 1) & 3)) << 3);   // swizzled chunk offset

#pragma unroll
  for (int kt = 0; kt < NKT; ++kt) {
    const int rsl = kt % 3;
    const int wof = ((kt + 2) % 3) * SLOT;
    const bf16_t* abase = &sm[rsl * SLOT + (wm * 64 + lr) * BK + co];
    const bf16_t* bbase = &sm[rsl * SLOT + ASL + (wn * 64 + lr) * BK + co];

    // ds_read the 8 fragments; slot rsl full since boundary kt-1.
    bf16x8 af[4], bfr[4];
#pragma unroll
    for (int i = 0; i < 4; ++i) {
      af[i]  = *(const bf16x8*)(abase + i * (16 * BK));
      bfr[i] = *(const bf16x8*)(bbase + i * (16 * BK));
    }
    // Stage kt+2 -> slot (kt+2)%3 (readers finished before boundary kt-1).
    if (kt + 2 < NKT) {
#pragma unroll
      for (int s = 0; s < 2; ++s)
        GLD(aSrc[s] + ofsA(kt + 2), wof + (s * 256 + tid) * 8);
#pragma unroll
      for (int s = 0; s < 2; ++s)
        GLD(bSrc[s] + (size_t)(kt + 2) * BK, wof + ASL + (s * 256 + tid) * 8);
    }
    // NO sched_barrier / lgkmcnt(0) pins here (the r7 change): compiler
    // emits progressive lgkmcnt so MFMA #1 starts when its 2 operands
    // land, and interleaves reads/GLD-issue/MFMA (m97 behavior).
    __builtin_amdgcn_s_setprio(1);
#pragma unroll
    for (int i = 0; i < 4; ++i)
#pragma unroll
      for (int j = 0; j < 4; ++j)
        acc[i][j] = __builtin_amdgcn_mfma_f32_16x16x32_bf16(
            af[i], bfr[j], acc[i][j], 0, 0, 0);
    __builtin_amdgcn_s_setprio(0);
    // Boundary: counted vmcnt (T4) -- kt+1's 4 loads landed, kt+2's 4 stay
    // in flight. vmcnt(0) only at the last staged boundary.
    if (kt + 2 < NKT)       asm volatile("s_waitcnt vmcnt(4)" ::: "memory");
    else if (kt + 2 == NKT) asm volatile("s_waitcnt vmcnt(0)" ::: "memory");
    if (kt + 1 < NKT) __builtin_amdgcn_s_barrier();
  }

  // Epilogue. C/D layout: col = lane&15, row = (lane>>4)*4 + reg  [m89]
  const int cn = lane & 15;
  const int rq = (lane >> 4) << 2;
  if constexpr (MODE == 0) {
    const int z  = n0 >> 9;                        // BN=128 | 512 -> z uniform
    const float* bias = (z == 0) ? b0 : (z == 1) ? b1 : b2;
    const int bb = m0 >> 12;
    const int t0 = m0 & (T_ - 1);
    bf16_t* plane = (bf16_t*)Outp + (size_t)z * PLANE;
#pragma unroll
    for (int j = 0; j < 4; ++j) {
      const int cc  = (n0 & (C_ - 1)) + wn * 64 + j * 16 + cn;
      const int hh  = cc >> 6, dd = cc & 63;
      const float bvv = bias[cc];
      bf16_t* hb = plane + ((size_t)(bb * H_ + hh) * T_) * D_ + dd;
#pragma unroll
      for (int i = 0; i < 4; ++i)
#pragma unroll
        for (int r = 0; r < 4; ++r) {
          const int t = t0 + wm * 64 + i * 16 + rq + r;
          hb[(size_t)t * D_] = (bf16_t)(acc[i][j][r] + bvv);
        }
    }
  } else {
    float* outp = (float*)Outp;
#pragma unroll
    for (int j = 0; j < 4; ++j) {
      const int n = n0 + wn * 64 + j * 16 + cn;
      const float bvv = b0[n];
#pragma unroll
      for (int i = 0; i < 4; ++i)
#pragma unroll
        for (int r = 0; r < 4; ++r) {
          const int m = m0 + wm * 64 + i * 16 + rq + r;
          outp[(size_t)m * C_ + n] = acc[i][j][r] + bvv;
        }
    }
  }
}

// ---------------------------------------------------------------------------
// Neighborhood attention: 8 threads per (b,h,t), d-octet each; width-8
// shfl_xor score reduce; per-head plane I/O (fully coalesced). Unchanged.
// ---------------------------------------------------------------------------
__global__ __launch_bounds__(256)
void attn_kernel(const bf16_t* __restrict__ qkv, bf16_t* __restrict__ y) {
  const int tid  = threadIdx.x;
  const int sub  = tid & 7;
  const int tl   = tid >> 3;
  const int t    = blockIdx.x * 32 + tl;
  const int h    = blockIdx.y;
  const int b    = blockIdx.z;

  const size_t pl = (size_t)(b * H_ + h) * T_ * D_;
  const bf16_t* q = qkv + pl;
  const bf16_t* k = qkv + (size_t)PLANE + pl;
  const bf16_t* v = qkv + (size_t)2 * PLANE + pl;
  const int c = sub * 8;

  int tj[KS_];
#pragma unroll
  for (int j = 0; j < KS_; ++j) {
    int tt = t - PAD_ + j;
    tj[j] = tt < 0 ? 0 : (tt >= T_ ? T_ - 1 : tt);
  }

  bf16x8 q8 = *(const bf16x8*)(q + (size_t)t * D_ + c);
  float qf[8];
#pragma unroll
  for (int e = 0; e < 8; ++e) qf[e] = (float)q8[e];

  float s[KS_];
#pragma unroll
  for (int j = 0; j < KS_; ++j) {
    bf16x8 k8 = *(const bf16x8*)(k + (size_t)tj[j] * D_ + c);
    float d0 = 0.f;
#pragma unroll
    for (int e = 0; e < 8; ++e) d0 += qf[e] * (float)k8[e];
    s[j] = d0;
  }

#pragma unroll
  for (int m = 1; m < 8; m <<= 1)
#pragma unroll
    for (int j = 0; j < KS_; ++j) s[j] += __shfl_xor(s[j], m, 8);

  float mx = s[0];
#pragma unroll
  for (int j = 1; j < KS_; ++j) mx = fmaxf(mx, s[j]);
  float w[KS_], sum = 0.f;
#pragma unroll
  for (int j = 0; j < KS_; ++j) {
    w[j] = __expf((s[j] - mx) * 0.125f);   // scale = 1/sqrt(64)
    sum += w[j];
  }
  const float inv = 1.f / sum;
#pragma unroll
  for (int j = 0; j < KS_; ++j) w[j] *= inv;

  float o[8] = {0.f, 0.f, 0.f, 0.f, 0.f, 0.f, 0.f, 0.f};
#pragma unroll
  for (int j = 0; j < KS_; ++j) {
    bf16x8 v8 = *(const bf16x8*)(v + (size_t)tj[j] * D_ + c);
#pragma unroll
    for (int e = 0; e < 8; ++e) o[e] += w[j] * (float)v8[e];
  }
  bf16x8 o8;
#pragma unroll
  for (int e = 0; e < 8; ++e) o8[e] = (bf16_t)o[e];
  *(bf16x8*)(y + pl + (size_t)t * D_ + c) = o8;
}

// ---------------------------------------------------------------------------
extern "C" void kernel_launch(void* const* d_in, const int* in_sizes, int n_in,
                              void* d_out, int out_size, void* d_ws, size_t ws_size,
                              hipStream_t stream) {
  const float* x  = (const float*)d_in[0];
  const float* Wq = (const float*)d_in[1];
  const float* bq = (const float*)d_in[2];
  const float* Wk = (const float*)d_in[3];
  const float* bk = (const float*)d_in[4];
  const float* Wv = (const float*)d_in[5];
  const float* bv = (const float*)d_in[6];
  const float* Wo = (const float*)d_in[7];
  const float* bo = (const float*)d_in[8];
  float* out = (float*)d_out;

  // Workspace: Wb 2MB | xb 16.8MB | qkv 50.3MB  (y aliases xb: xb is dead
  // once gemm8p<0> completes; attn writes y, gemm8p<1> reads it). ~69MB.
  bf16_t* Wb  = (bf16_t*)d_ws;
  bf16_t* xb  = Wb + (size_t)4 * C_ * C_;
  bf16_t* qkv = xb + (size_t)PLANE;
  bf16_t* y   = xb;

  conv_all<<<(4 * WU + PLANE / 8) / 256, 256, 0, stream>>>(Wq, Wk, Wv, Wo, x, Wb, xb);
  gemm8p<0><<<dim3(3 * C_ / BN, MTOT / BM), 256, 0, stream>>>(
      xb, Wb, bq, bk, bv, qkv);
  attn_kernel<<<dim3(T_ / 32, H_, B_), 256, 0, stream>>>(qkv, y);
  gemm8p<1><<<dim3(C_ / BN, MTOT / BM), 256, 0, stream>>>(
      y, Wb + (size_t)3 * C_ * C_, bo, nullptr, nullptr, out);
}